// Round 9
// baseline (206.679 us; speedup 1.0000x reference)
//
#include <hip/hip_runtime.h>

// HetConv2d, three-phase:
//  0) build_frags: precompute per-(pair,lane) MFMA A-fragments + bias into
//     d_ws (45 KB, L2-resident).
//  1) prepass: x NCHW f32 -> zero-padded NHWC bf16 x' (d_ws), swizzle baked:
//     byte-in-pixel = (c*2) ^ ((wp&7)<<4).
//  2) hetconv_main: round-7 structure (8192 blocks, one 4x32 tile each),
//     global_load_lds staging, taps-outer compute; 6 blocks/CU occupancy
//     (launch_bounds(256,6)), plain coalesced stores (L2 merges 64B halves).
// Fallback: round-2 fused kernel if ws too small.

#define HH 256
#define WW 256
#define CCH 64
#define HW (HH * WW)
#define NB 16
#define PH 258
#define PW 258
#define TH 4
#define TW 32
#define HROWS (TH + 2)              // 6
#define HCOLS (TW + 2)              // 34
#define NPIX (HROWS * HCOLS)        // 204
#define ROWB (HCOLS * CCH * 2)      // 4352 bytes per LDS tile row
#define NCHUNK (NPIX * 8)           // 1632 16B chunks per tile

#define XQ_BYTES ((size_t)NB * PH * PW * CCH * 2)   // 136,315,392 (16B-aligned)
#define NSLOT 22                                     // 4 fc + 16 ft + 2 bias
#define FRAG_BYTES (2 * NSLOT * 64 * 16)             // 45056

typedef __attribute__((ext_vector_type(8))) short bf16x8;
typedef __attribute__((ext_vector_type(4))) float f32x4;
typedef __attribute__((ext_vector_type(4))) unsigned int u32x4;

typedef __attribute__((address_space(1))) const unsigned int gu32;
typedef __attribute__((address_space(3))) unsigned int lu32;

__device__ __forceinline__ unsigned short f2bf(float f) {
    unsigned int u = __float_as_uint(f);
    u += 0x7FFFu + ((u >> 16) & 1u);   // RNE
    return (unsigned short)(u >> 16);
}

// ---------------- phase 0: fragment build (1 block, 128 threads) ----------
__global__ __launch_bounds__(128) void build_frags(
    const float* __restrict__ w3, const float* __restrict__ w1,
    const float* __restrict__ b, u32x4* __restrict__ frag)
{
    const int tid = threadIdx.x;
    if (tid >= 128) return;
    const int pair = tid >> 6;
    const int lane = tid & 63;
    const int l15  = lane & 15;
    const int lq   = lane >> 4;

    const int ia = pair * 16 + l15;
    const int ib = ia + 32;

    u32x4* out = frag + (size_t)pair * NSLOT * 64 + lane;

    // fc[mt][kh]: slots 0..3
    #pragma unroll
    for (int mt = 0; mt < 2; ++mt) {
        const int i = mt ? ib : ia;
        #pragma unroll
        for (int kh = 0; kh < 2; ++kh) {
            const int c0 = kh * 32 + lq * 8;
            bf16x8 v;
            #pragma unroll
            for (int e = 0; e < 8; ++e) {
                const int j = c0 + e;
                const float wval = (((j ^ i) & 31) == 0)
                                   ? w3[((size_t)i * CCH + j) * 9 + 4]
                                   : w1[(size_t)i * CCH + j];
                v[e] = (short)f2bf(wval);
            }
            out[(mt * 2 + kh) * 64] = __builtin_bit_cast(u32x4, v);
        }
    }

    // ft[mt][ti]: slots 4..19
    const bool avalid = ((lq & 1) == (l15 >> 3));
    const int  epos   = l15 & 7;
    const int  jcol   = pair * 16 + l15 + 32 * (lane >> 5);
    #pragma unroll
    for (int mt = 0; mt < 2; ++mt) {
        const int i = mt ? ib : ia;
        const float* wp = w3 + ((size_t)i * CCH + jcol) * 9;
        int ti = 0;
        #pragma unroll
        for (int t = 0; t < 9; ++t) {
            if (t == 4) continue;
            const float val = avalid ? wp[t] : 0.0f;
            const short bv = (short)f2bf(val);
            bf16x8 f;
            #pragma unroll
            for (int e2 = 0; e2 < 8; ++e2) f[e2] = (e2 == epos) ? bv : (short)0;
            out[(4 + mt * 8 + ti) * 64] = __builtin_bit_cast(u32x4, f);
            ++ti;
        }
    }

    // bias[mt]: slots 20..21
    #pragma unroll
    for (int mt = 0; mt < 2; ++mt) {
        const int chb = (mt ? 32 : 0) + pair * 16 + lq * 4;
        f32x4 bv = (f32x4){b[chb + 0], b[chb + 1], b[chb + 2], b[chb + 3]};
        out[(20 + mt) * 64] = __builtin_bit_cast(u32x4, bv);
    }
}

// ---------------- phase 1: pre-pass, one padded row per block -------------
__global__ __launch_bounds__(256) void prepass(
    const float* __restrict__ x, unsigned short* __restrict__ xq)
{
    __shared__ __align__(16) unsigned short s[256 * CCH];   // 32 KB
    const int t  = threadIdx.x;
    const int hp = blockIdx.x;            // 0..PH-1
    const int n  = blockIdx.y;
    char* sb = (char*)s;
    unsigned short* rowp = xq + ((size_t)(n * PH + hp)) * PW * CCH;
    const int NCH16 = PW * CCH / 8;       // 2064 16B chunks per padded row

    if (hp == 0 || hp == PH - 1) {
        const u32x4 z = (u32x4){0u, 0u, 0u, 0u};
        for (int i = t; i < NCH16; i += 256)
            *(u32x4*)((char*)rowp + (size_t)i * 16) = z;
        return;
    }

    const int h = hp - 1;
    const float* xp = x + (size_t)n * CCH * HW + (size_t)h * WW + t;  // t = w
    #pragma unroll 4
    for (int c4 = 0; c4 < CCH; c4 += 4) {
        float v0 = __builtin_nontemporal_load(xp + (size_t)(c4 + 0) * HW);
        float v1 = __builtin_nontemporal_load(xp + (size_t)(c4 + 1) * HW);
        float v2 = __builtin_nontemporal_load(xp + (size_t)(c4 + 2) * HW);
        float v3 = __builtin_nontemporal_load(xp + (size_t)(c4 + 3) * HW);
        uint2 pk;
        pk.x = (unsigned)f2bf(v0) | ((unsigned)f2bf(v1) << 16);
        pk.y = (unsigned)f2bf(v2) | ((unsigned)f2bf(v3) << 16);
        *(uint2*)(sb + (t << 7) + ((c4 << 1) ^ ((t & 7) << 4))) = pk;
    }
    __syncthreads();

    for (int i = t; i < NCH16; i += 256) {
        const int wp = i >> 3;
        const int s8 = i & 7;
        u32x4 v;
        if (wp == 0 || wp == PW - 1) {
            v = (u32x4){0u, 0u, 0u, 0u};
        } else {
            const int r = wp - 1;
            const int cslot = s8 ^ (wp & 7);
            v = *(const u32x4*)(sb + (r << 7) + ((cslot ^ (r & 7)) << 4));
        }
        *(u32x4*)((char*)rowp + (size_t)i * 16) = v;
    }
}

// ---------------- phase 2: main conv (taps-outer compute) ----------------
__global__ __launch_bounds__(256, 6) void hetconv_main(
    const unsigned short* __restrict__ xq, const u32x4* __restrict__ frag,
    float* __restrict__ y)
{
    __shared__ __align__(16) unsigned short s_x[NPIX * CCH];   // 26112 B

    const int tid  = threadIdx.x;
    const int lane = tid & 63;
    const int wv   = tid >> 6;
    const int l15  = lane & 15;
    const int lq   = lane >> 4;
    const int pair  = wv & 1;
    const int trow0 = (wv >> 1) * 2;

    const int n  = blockIdx.z;
    const int h0 = blockIdx.y * TH;      // padded top row of tile
    const int w0 = blockIdx.x * TW;      // padded left col (w0 % 8 == 0)
    const size_t nbase = (size_t)n * CCH * HW;

    // ---- stage tile: 1632 coalesced 16B chunks, linear LDS ----
    {
        const unsigned short* gsrc =
            xq + ((size_t)(n * PH + h0) * PW + w0) * CCH;
        #pragma unroll
        for (int it = 0; it < 7; ++it) {
            const int ck = it * 256 + tid;
            if (it < 6 || tid < (NCHUNK - 6 * 256)) {
                const int r = ck / (HCOLS * 8);            // 272 chunks/row
                const int o = ck - r * (HCOLS * 8);
                const unsigned short* gp = gsrc + (size_t)r * PW * CCH + o * 8;
                __builtin_amdgcn_global_load_lds(
                    (gu32*)(const void*)gp,
                    (lu32*)(void*)((char*)s_x + ck * 16), 16, 0, 0);
            }
        }
    }

    __syncthreads();

    // ---- compute from LDS, taps outer / pixel-group inner ----
    const char* lbase = (const char*)s_x;
    const u32x4* fb = frag + (size_t)pair * NSLOT * 64 + lane;
    const int c0t = pair * 16 + (lq & 1) * 8 + 32 * (lane >> 5);

    f32x4 acc[4][2];
    #pragma unroll
    for (int g = 0; g < 4; ++g)
        #pragma unroll
        for (int mt = 0; mt < 2; ++mt)
            acc[g][mt] = (f32x4){0.f, 0.f, 0.f, 0.f};

    // center tap (dy=1, dx=1): dense K=64, fc fragments slots 0..3
    #pragma unroll
    for (int kh = 0; kh < 2; ++kh) {
        const bf16x8 f0 = __builtin_bit_cast(bf16x8, fb[(0 * 2 + kh) * 64]);
        const bf16x8 f1 = __builtin_bit_cast(bf16x8, fb[(1 * 2 + kh) * 64]);
        const int c = kh * 32 + lq * 8;
        #pragma unroll
        for (int g = 0; g < 4; ++g) {
            const int row = trow0 + (g >> 1);
            const int p   = (g & 1) * 16 + l15 + 1;
            const bf16x8 bf = *(const bf16x8*)(lbase + (row + 1) * ROWB + (p << 7)
                                               + ((c << 1) ^ ((p & 7) << 4)));
            acc[g][0] = __builtin_amdgcn_mfma_f32_16x16x32_bf16(f0, bf, acc[g][0], 0, 0, 0);
            acc[g][1] = __builtin_amdgcn_mfma_f32_16x16x32_bf16(f1, bf, acc[g][1], 0, 0, 0);
        }
    }

    // 8 off-center taps, packed K=32, ft fragments slots 4..19
    {
        int ti = 0;
        #pragma unroll
        for (int t = 0; t < 9; ++t) {
            if (t == 4) continue;
            const int dy = t / 3, dx = t % 3;
            const bf16x8 f0 = __builtin_bit_cast(bf16x8, fb[(4 + ti) * 64]);
            const bf16x8 f1 = __builtin_bit_cast(bf16x8, fb[(4 + 8 + ti) * 64]);
            #pragma unroll
            for (int g = 0; g < 4; ++g) {
                const int row = trow0 + (g >> 1);
                const int p   = (g & 1) * 16 + l15 + dx;
                const bf16x8 bf = *(const bf16x8*)(lbase + (row + dy) * ROWB + (p << 7)
                                                   + ((c0t << 1) ^ ((p & 7) << 4)));
                acc[g][0] = __builtin_amdgcn_mfma_f32_16x16x32_bf16(f0, bf, acc[g][0], 0, 0, 0);
                acc[g][1] = __builtin_amdgcn_mfma_f32_16x16x32_bf16(f1, bf, acc[g][1], 0, 0, 0);
            }
            ++ti;
        }
    }

    // bias (slots 20..21)
    f32x4 bias_[2];
    #pragma unroll
    for (int mt = 0; mt < 2; ++mt)
        bias_[mt] = __builtin_bit_cast(f32x4, fb[(20 + mt) * 64]);

    // ---- store (plain, coalesced; L2 merges the two 64B halves) ----
    #pragma unroll
    for (int g = 0; g < 4; ++g) {
        const int row = trow0 + (g >> 1);
        const int gc  = (g & 1) * 16;
        const int gh  = h0 + row;
        const int gw  = w0 + gc + l15;
        #pragma unroll
        for (int mt = 0; mt < 2; ++mt) {
            const int chb = (mt ? 32 : 0) + pair * 16 + lq * 4;
            #pragma unroll
            for (int r = 0; r < 4; ++r) {
                y[nbase + (size_t)(chb + r) * HW + (size_t)gh * WW + gw] =
                    acc[g][mt][r] + bias_[mt][r];
            }
        }
    }
}

// ---------------- fallback: round-2 fused kernel (proven) ----------------
__global__ __launch_bounds__(256, 2) void hetconv_mfma(
    const float* __restrict__ x, const float* __restrict__ w3,
    const float* __restrict__ w1, const float* __restrict__ b,
    float* __restrict__ y)
{
    __shared__ __align__(16) unsigned short s_x[NPIX * CCH];

    const int tid  = threadIdx.x;
    const int lane = tid & 63;
    const int wv   = tid >> 6;
    const int l15  = lane & 15;
    const int lq   = lane >> 4;
    const int pair  = wv & 1;
    const int trow0 = (wv >> 1) * 2;

    const int n  = blockIdx.z;
    const int h0 = blockIdx.y * TH;
    const int w0 = blockIdx.x * TW;
    const size_t nbase = (size_t)n * CCH * HW;

    if (tid < NPIX) {
        const int r = tid / HCOLS;
        const int c = tid - r * HCOLS;
        const int gh = h0 + r - 1;
        const int gw = w0 + c - 1;
        const bool inb = ((unsigned)gh < HH) && ((unsigned)gw < WW);
        const float* xp = x + nbase + (size_t)(inb ? gh : 0) * WW + (inb ? gw : 0);
        char* lbase = (char*)s_x;
        #pragma unroll 4
        for (int c4 = 0; c4 < CCH; c4 += 4) {
            float v0 = inb ? xp[(size_t)(c4 + 0) * HW] : 0.0f;
            float v1 = inb ? xp[(size_t)(c4 + 1) * HW] : 0.0f;
            float v2 = inb ? xp[(size_t)(c4 + 2) * HW] : 0.0f;
            float v3 = inb ? xp[(size_t)(c4 + 3) * HW] : 0.0f;
            uint2 pk;
            pk.x = (unsigned)f2bf(v0) | ((unsigned)f2bf(v1) << 16);
            pk.y = (unsigned)f2bf(v2) | ((unsigned)f2bf(v3) << 16);
            *(uint2*)(lbase + (tid << 7) + ((c4 << 1) ^ ((tid & 7) << 4))) = pk;
        }
    }

    const int ia = pair * 16 + l15;
    const int ib = ia + 32;
    bf16x8 fc[2][2];
    #pragma unroll
    for (int mt = 0; mt < 2; ++mt) {
        const int i = mt ? ib : ia;
        #pragma unroll
        for (int kh = 0; kh < 2; ++kh) {
            const int c0 = kh * 32 + lq * 8;
            bf16x8 v;
            #pragma unroll
            for (int e = 0; e < 8; ++e) {
                const int j = c0 + e;
                const float wval = (((j ^ i) & 31) == 0)
                                   ? w3[((size_t)i * CCH + j) * 9 + 4]
                                   : w1[(size_t)i * CCH + j];
                v[e] = (short)f2bf(wval);
            }
            fc[mt][kh] = v;
        }
    }
    const bool avalid = ((lq & 1) == (l15 >> 3));
    const int  epos   = l15 & 7;
    const int  jcol   = pair * 16 + l15 + 32 * (lane >> 5);
    bf16x8 ft[2][8];
    #pragma unroll
    for (int mt = 0; mt < 2; ++mt) {
        const int i = mt ? ib : ia;
        const float* wp = w3 + ((size_t)i * CCH + jcol) * 9;
        int ti = 0;
        #pragma unroll
        for (int t = 0; t < 9; ++t) {
            if (t == 4) continue;
            const float val = avalid ? wp[t] : 0.0f;
            const short bv = (short)f2bf(val);
            bf16x8 f;
            #pragma unroll
            for (int e2 = 0; e2 < 8; ++e2) f[e2] = (e2 == epos) ? bv : (short)0;
            ft[mt][ti] = f;
            ++ti;
        }
    }
    float bias_[2][4];
    #pragma unroll
    for (int mt = 0; mt < 2; ++mt) {
        const int chb = (mt ? 32 : 0) + pair * 16 + lq * 4;
        #pragma unroll
        for (int r = 0; r < 4; ++r) bias_[mt][r] = b[chb + r];
    }
    __syncthreads();

    const char* lbase = (const char*)s_x;
    const int c0t = pair * 16 + (lq & 1) * 8 + 32 * (lane >> 5);
    f32x4 acc[4][2];
    #pragma unroll
    for (int g = 0; g < 4; ++g)
        #pragma unroll
        for (int mt = 0; mt < 2; ++mt)
            acc[g][mt] = (f32x4){0.f, 0.f, 0.f, 0.f};

    #pragma unroll
    for (int g = 0; g < 4; ++g) {
        const int row = trow0 + (g >> 1);
        const int gc  = (g & 1) * 16;
        {
            const int p = (row + 1) * HCOLS + gc + l15 + 1;
            #pragma unroll
            for (int kh = 0; kh < 2; ++kh) {
                const int c = kh * 32 + lq * 8;
                const bf16x8 bf = *(const bf16x8*)(lbase + (p << 7) + ((c << 1) ^ ((p & 7) << 4)));
                acc[g][0] = __builtin_amdgcn_mfma_f32_16x16x32_bf16(fc[0][kh], bf, acc[g][0], 0, 0, 0);
                acc[g][1] = __builtin_amdgcn_mfma_f32_16x16x32_bf16(fc[1][kh], bf, acc[g][1], 0, 0, 0);
            }
        }
        int ti = 0;
        #pragma unroll
        for (int t = 0; t < 9; ++t) {
            if (t == 4) continue;
            const int dy = t / 3, dx = t % 3;
            const int p = (row + dy) * HCOLS + gc + l15 + dx;
            const bf16x8 bf = *(const bf16x8*)(lbase + (p << 7) + ((c0t << 1) ^ ((p & 7) << 4)));
            acc[g][0] = __builtin_amdgcn_mfma_f32_16x16x32_bf16(ft[0][ti], bf, acc[g][0], 0, 0, 0);
            acc[g][1] = __builtin_amdgcn_mfma_f32_16x16x32_bf16(ft[1][ti], bf, acc[g][1], 0, 0, 0);
            ++ti;
        }
    }

    #pragma unroll
    for (int g = 0; g < 4; ++g) {
        const int row = trow0 + (g >> 1);
        const int gc  = (g & 1) * 16;
        const int gh  = h0 + row;
        const int gw  = w0 + gc + l15;
        #pragma unroll
        for (int mt = 0; mt < 2; ++mt) {
            const int chb = (mt ? 32 : 0) + pair * 16 + lq * 4;
            #pragma unroll
            for (int r = 0; r < 4; ++r) {
                y[nbase + (size_t)(chb + r) * HW + (size_t)gh * WW + gw] =
                    acc[g][mt][r] + bias_[mt][r];
            }
        }
    }
}

extern "C" void kernel_launch(void* const* d_in, const int* in_sizes, int n_in,
                              void* d_out, int out_size, void* d_ws, size_t ws_size,
                              hipStream_t stream) {
    (void)in_sizes; (void)n_in; (void)out_size;
    const float* x  = (const float*)d_in[0];
    const float* w3 = (const float*)d_in[1];
    const float* w1 = (const float*)d_in[2];
    const float* b  = (const float*)d_in[3];
    float* y = (float*)d_out;

    const size_t need = XQ_BYTES + FRAG_BYTES;
    if (ws_size >= need) {
        unsigned short* xq = (unsigned short*)d_ws;
        u32x4* frag = (u32x4*)((char*)d_ws + XQ_BYTES);
        hipLaunchKernelGGL(build_frags, dim3(1, 1, 1), dim3(128, 1, 1), 0, stream,
                           w3, w1, b, frag);
        hipLaunchKernelGGL(prepass, dim3(PH, NB, 1), dim3(256, 1, 1), 0, stream, x, xq);
        hipLaunchKernelGGL(hetconv_main, dim3(WW / TW, HH / TH, NB), dim3(256, 1, 1),
                           0, stream, xq, frag, y);
    } else {
        hipLaunchKernelGGL(hetconv_mfma, dim3(WW / TW, HH / TH, NB), dim3(256, 1, 1),
                           0, stream, x, w3, w1, b, y);
    }
}

// Round 10
// 170.115 us; speedup vs baseline: 1.2149x; 1.2149x over previous
//
#include <hip/hip_runtime.h>

// HetConv2d, three-phase:
//  0) build_frags: precompute per-(pair,lane) MFMA A-fragments + bias into
//     d_ws (45 KB, L2-resident).
//  1) prepass: x NCHW f32 -> zero-padded NHWC bf16 x' (d_ws), swizzle baked:
//     byte-in-pixel = (c*2) ^ ((wp&7)<<4).
//  2) hetconv_main: 4096 blocks; each stages ONE shared-halo 6x66 region via
//     global_load_lds (50.7 KB LDS), one barrier, then computes TWO 4x32
//     subtiles (taps-outer, 80 MFMA per drain). NONTEMPORAL stores (keep L2
//     clean for xq staging reads — plain stores cost +46us, r9 A/B).
// Fallback: round-2 fused kernel if ws too small.

#define HH 256
#define WW 256
#define CCH 64
#define HW (HH * WW)
#define NB 16
#define PH 258
#define PW 258
#define TH 4
#define TW 32
#define RCOLS 66                    // staged region cols (2 subtiles + halo)
#define RROWS 6                     // staged region rows
#define RPIX (RROWS * RCOLS)        // 396
#define ROWB (RCOLS * CCH * 2)      // 8448 bytes per LDS region row
#define NCHUNK2 (RPIX * 8)          // 3168 16B chunks per region

#define XQ_BYTES ((size_t)NB * PH * PW * CCH * 2)   // 136,315,392 (16B-aligned)
#define NSLOT 22                                     // 4 fc + 16 ft + 2 bias
#define FRAG_BYTES (2 * NSLOT * 64 * 16)             // 45056

typedef __attribute__((ext_vector_type(8))) short bf16x8;
typedef __attribute__((ext_vector_type(4))) float f32x4;
typedef __attribute__((ext_vector_type(4))) unsigned int u32x4;

typedef __attribute__((address_space(1))) const unsigned int gu32;
typedef __attribute__((address_space(3))) unsigned int lu32;

__device__ __forceinline__ unsigned short f2bf(float f) {
    unsigned int u = __float_as_uint(f);
    u += 0x7FFFu + ((u >> 16) & 1u);   // RNE
    return (unsigned short)(u >> 16);
}

// ---------------- phase 0: fragment build (1 block, 128 threads) ----------
__global__ __launch_bounds__(128) void build_frags(
    const float* __restrict__ w3, const float* __restrict__ w1,
    const float* __restrict__ b, u32x4* __restrict__ frag)
{
    const int tid = threadIdx.x;
    if (tid >= 128) return;
    const int pair = tid >> 6;
    const int lane = tid & 63;
    const int l15  = lane & 15;
    const int lq   = lane >> 4;

    const int ia = pair * 16 + l15;
    const int ib = ia + 32;

    u32x4* out = frag + (size_t)pair * NSLOT * 64 + lane;

    // fc[mt][kh]: slots 0..3
    #pragma unroll
    for (int mt = 0; mt < 2; ++mt) {
        const int i = mt ? ib : ia;
        #pragma unroll
        for (int kh = 0; kh < 2; ++kh) {
            const int c0 = kh * 32 + lq * 8;
            bf16x8 v;
            #pragma unroll
            for (int e = 0; e < 8; ++e) {
                const int j = c0 + e;
                const float wval = (((j ^ i) & 31) == 0)
                                   ? w3[((size_t)i * CCH + j) * 9 + 4]
                                   : w1[(size_t)i * CCH + j];
                v[e] = (short)f2bf(wval);
            }
            out[(mt * 2 + kh) * 64] = __builtin_bit_cast(u32x4, v);
        }
    }

    // ft[mt][ti]: slots 4..19
    const bool avalid = ((lq & 1) == (l15 >> 3));
    const int  epos   = l15 & 7;
    const int  jcol   = pair * 16 + l15 + 32 * (lane >> 5);
    #pragma unroll
    for (int mt = 0; mt < 2; ++mt) {
        const int i = mt ? ib : ia;
        const float* wp = w3 + ((size_t)i * CCH + jcol) * 9;
        int ti = 0;
        #pragma unroll
        for (int t = 0; t < 9; ++t) {
            if (t == 4) continue;
            const float val = avalid ? wp[t] : 0.0f;
            const short bv = (short)f2bf(val);
            bf16x8 f;
            #pragma unroll
            for (int e2 = 0; e2 < 8; ++e2) f[e2] = (e2 == epos) ? bv : (short)0;
            out[(4 + mt * 8 + ti) * 64] = __builtin_bit_cast(u32x4, f);
            ++ti;
        }
    }

    // bias[mt]: slots 20..21
    #pragma unroll
    for (int mt = 0; mt < 2; ++mt) {
        const int chb = (mt ? 32 : 0) + pair * 16 + lq * 4;
        f32x4 bv = (f32x4){b[chb + 0], b[chb + 1], b[chb + 2], b[chb + 3]};
        out[(20 + mt) * 64] = __builtin_bit_cast(u32x4, bv);
    }
}

// ---------------- phase 1: pre-pass, one padded row per block -------------
__global__ __launch_bounds__(256) void prepass(
    const float* __restrict__ x, unsigned short* __restrict__ xq)
{
    __shared__ __align__(16) unsigned short s[256 * CCH];   // 32 KB
    const int t  = threadIdx.x;
    const int hp = blockIdx.x;            // 0..PH-1
    const int n  = blockIdx.y;
    char* sb = (char*)s;
    unsigned short* rowp = xq + ((size_t)(n * PH + hp)) * PW * CCH;
    const int NCH16 = PW * CCH / 8;       // 2064 16B chunks per padded row

    if (hp == 0 || hp == PH - 1) {
        const u32x4 z = (u32x4){0u, 0u, 0u, 0u};
        for (int i = t; i < NCH16; i += 256)
            *(u32x4*)((char*)rowp + (size_t)i * 16) = z;
        return;
    }

    const int h = hp - 1;
    const float* xp = x + (size_t)n * CCH * HW + (size_t)h * WW + t;  // t = w
    #pragma unroll 4
    for (int c4 = 0; c4 < CCH; c4 += 4) {
        float v0 = __builtin_nontemporal_load(xp + (size_t)(c4 + 0) * HW);
        float v1 = __builtin_nontemporal_load(xp + (size_t)(c4 + 1) * HW);
        float v2 = __builtin_nontemporal_load(xp + (size_t)(c4 + 2) * HW);
        float v3 = __builtin_nontemporal_load(xp + (size_t)(c4 + 3) * HW);
        uint2 pk;
        pk.x = (unsigned)f2bf(v0) | ((unsigned)f2bf(v1) << 16);
        pk.y = (unsigned)f2bf(v2) | ((unsigned)f2bf(v3) << 16);
        *(uint2*)(sb + (t << 7) + ((c4 << 1) ^ ((t & 7) << 4))) = pk;
    }
    __syncthreads();

    for (int i = t; i < NCH16; i += 256) {
        const int wp = i >> 3;
        const int s8 = i & 7;
        u32x4 v;
        if (wp == 0 || wp == PW - 1) {
            v = (u32x4){0u, 0u, 0u, 0u};
        } else {
            const int r = wp - 1;
            const int cslot = s8 ^ (wp & 7);
            v = *(const u32x4*)(sb + (r << 7) + ((cslot ^ (r & 7)) << 4));
        }
        *(u32x4*)((char*)rowp + (size_t)i * 16) = v;
    }
}

// ---------------- phase 2: main conv (6x66 region, 2 subtiles) ------------
__global__ __launch_bounds__(256, 3) void hetconv_main(
    const unsigned short* __restrict__ xq, const u32x4* __restrict__ frag,
    float* __restrict__ y)
{
    __shared__ __align__(16) unsigned short s_x[RPIX * CCH];   // 50688 B

    const int tid  = threadIdx.x;
    const int lane = tid & 63;
    const int wv   = tid >> 6;
    const int l15  = lane & 15;
    const int lq   = lane >> 4;
    const int pair  = wv & 1;
    const int trow0 = (wv >> 1) * 2;

    const int n  = blockIdx.z;
    const int h0 = blockIdx.y * TH;      // padded top row of region
    const int w0 = blockIdx.x * 64;      // padded left col of region (w0 % 8 == 0)
    const size_t nbase = (size_t)n * CCH * HW;

    // ---- stage region: 3168 coalesced 16B chunks, linear LDS ----
    {
        const unsigned short* gsrc =
            xq + ((size_t)(n * PH + h0) * PW + w0) * CCH;
        #pragma unroll
        for (int it = 0; it < 13; ++it) {
            const int ck = it * 256 + tid;
            if (it < 12 || tid < (NCHUNK2 - 12 * 256)) {
                const int r = ck / (RCOLS * 8);            // 528 chunks/row
                const int o = ck - r * (RCOLS * 8);
                const unsigned short* gp = gsrc + (size_t)r * PW * CCH + o * 8;
                __builtin_amdgcn_global_load_lds(
                    (gu32*)(const void*)gp,
                    (lu32*)(void*)((char*)s_x + ck * 16), 16, 0, 0);
            }
        }
    }

    const u32x4* fb = frag + (size_t)pair * NSLOT * 64 + lane;
    const int c0t = pair * 16 + (lq & 1) * 8 + 32 * (lane >> 5);

    // bias (slots 20..21) — load before barrier to overlap
    f32x4 bias_[2];
    #pragma unroll
    for (int mt = 0; mt < 2; ++mt)
        bias_[mt] = __builtin_bit_cast(f32x4, fb[(20 + mt) * 64]);

    __syncthreads();

    const char* lbase = (const char*)s_x;

    // ---- two 4x32 subtiles from the shared region ----
    #pragma unroll
    for (int s = 0; s < 2; ++s) {
        const int bs = s * 32;               // subtile base col in region

        f32x4 acc[4][2];
        #pragma unroll
        for (int g = 0; g < 4; ++g)
            #pragma unroll
            for (int mt = 0; mt < 2; ++mt)
                acc[g][mt] = (f32x4){0.f, 0.f, 0.f, 0.f};

        // center tap (dy=1, dx=1): dense K=64, fc slots 0..3
        #pragma unroll
        for (int kh = 0; kh < 2; ++kh) {
            const bf16x8 f0 = __builtin_bit_cast(bf16x8, fb[(0 * 2 + kh) * 64]);
            const bf16x8 f1 = __builtin_bit_cast(bf16x8, fb[(1 * 2 + kh) * 64]);
            const int c = kh * 32 + lq * 8;
            #pragma unroll
            for (int g = 0; g < 4; ++g) {
                const int row = trow0 + (g >> 1);
                const int p   = bs + (g & 1) * 16 + l15 + 1;
                const bf16x8 bf = *(const bf16x8*)(lbase + (row + 1) * ROWB + (p << 7)
                                                   + ((c << 1) ^ ((p & 7) << 4)));
                acc[g][0] = __builtin_amdgcn_mfma_f32_16x16x32_bf16(f0, bf, acc[g][0], 0, 0, 0);
                acc[g][1] = __builtin_amdgcn_mfma_f32_16x16x32_bf16(f1, bf, acc[g][1], 0, 0, 0);
            }
        }

        // 8 off-center taps, packed K=32, ft slots 4..19
        {
            int ti = 0;
            #pragma unroll
            for (int t = 0; t < 9; ++t) {
                if (t == 4) continue;
                const int dy = t / 3, dx = t % 3;
                const bf16x8 f0 = __builtin_bit_cast(bf16x8, fb[(4 + ti) * 64]);
                const bf16x8 f1 = __builtin_bit_cast(bf16x8, fb[(4 + 8 + ti) * 64]);
                #pragma unroll
                for (int g = 0; g < 4; ++g) {
                    const int row = trow0 + (g >> 1);
                    const int p   = bs + (g & 1) * 16 + l15 + dx;
                    const bf16x8 bf = *(const bf16x8*)(lbase + (row + dy) * ROWB + (p << 7)
                                                       + ((c0t << 1) ^ ((p & 7) << 4)));
                    acc[g][0] = __builtin_amdgcn_mfma_f32_16x16x32_bf16(f0, bf, acc[g][0], 0, 0, 0);
                    acc[g][1] = __builtin_amdgcn_mfma_f32_16x16x32_bf16(f1, bf, acc[g][1], 0, 0, 0);
                }
                ++ti;
            }
        }

        // ---- store (nontemporal: keep L2 clean for xq reads) ----
        #pragma unroll
        for (int g = 0; g < 4; ++g) {
            const int row = trow0 + (g >> 1);
            const int gc  = (g & 1) * 16;
            const int gh  = h0 + row;
            const int gw  = w0 + bs + gc + l15;
            #pragma unroll
            for (int mt = 0; mt < 2; ++mt) {
                const int chb = (mt ? 32 : 0) + pair * 16 + lq * 4;
                #pragma unroll
                for (int r = 0; r < 4; ++r) {
                    __builtin_nontemporal_store(
                        acc[g][mt][r] + bias_[mt][r],
                        y + nbase + (size_t)(chb + r) * HW + (size_t)gh * WW + gw);
                }
            }
        }
    }
}

// ---------------- fallback: round-2 fused kernel (proven) ----------------
#define HCOLS (TW + 2)
#define NPIX ((TH + 2) * HCOLS)

__global__ __launch_bounds__(256, 2) void hetconv_mfma(
    const float* __restrict__ x, const float* __restrict__ w3,
    const float* __restrict__ w1, const float* __restrict__ b,
    float* __restrict__ y)
{
    __shared__ __align__(16) unsigned short s_x[NPIX * CCH];

    const int tid  = threadIdx.x;
    const int lane = tid & 63;
    const int wv   = tid >> 6;
    const int l15  = lane & 15;
    const int lq   = lane >> 4;
    const int pair  = wv & 1;
    const int trow0 = (wv >> 1) * 2;

    const int n  = blockIdx.z;
    const int h0 = blockIdx.y * TH;
    const int w0 = blockIdx.x * TW;
    const size_t nbase = (size_t)n * CCH * HW;

    if (tid < NPIX) {
        const int r = tid / HCOLS;
        const int c = tid - r * HCOLS;
        const int gh = h0 + r - 1;
        const int gw = w0 + c - 1;
        const bool inb = ((unsigned)gh < HH) && ((unsigned)gw < WW);
        const float* xp = x + nbase + (size_t)(inb ? gh : 0) * WW + (inb ? gw : 0);
        char* lbase = (char*)s_x;
        #pragma unroll 4
        for (int c4 = 0; c4 < CCH; c4 += 4) {
            float v0 = inb ? xp[(size_t)(c4 + 0) * HW] : 0.0f;
            float v1 = inb ? xp[(size_t)(c4 + 1) * HW] : 0.0f;
            float v2 = inb ? xp[(size_t)(c4 + 2) * HW] : 0.0f;
            float v3 = inb ? xp[(size_t)(c4 + 3) * HW] : 0.0f;
            uint2 pk;
            pk.x = (unsigned)f2bf(v0) | ((unsigned)f2bf(v1) << 16);
            pk.y = (unsigned)f2bf(v2) | ((unsigned)f2bf(v3) << 16);
            *(uint2*)(lbase + (tid << 7) + ((c4 << 1) ^ ((tid & 7) << 4))) = pk;
        }
    }

    const int ia = pair * 16 + l15;
    const int ib = ia + 32;
    bf16x8 fc[2][2];
    #pragma unroll
    for (int mt = 0; mt < 2; ++mt) {
        const int i = mt ? ib : ia;
        #pragma unroll
        for (int kh = 0; kh < 2; ++kh) {
            const int c0 = kh * 32 + lq * 8;
            bf16x8 v;
            #pragma unroll
            for (int e = 0; e < 8; ++e) {
                const int j = c0 + e;
                const float wval = (((j ^ i) & 31) == 0)
                                   ? w3[((size_t)i * CCH + j) * 9 + 4]
                                   : w1[(size_t)i * CCH + j];
                v[e] = (short)f2bf(wval);
            }
            fc[mt][kh] = v;
        }
    }
    const bool avalid = ((lq & 1) == (l15 >> 3));
    const int  epos   = l15 & 7;
    const int  jcol   = pair * 16 + l15 + 32 * (lane >> 5);
    bf16x8 ft[2][8];
    #pragma unroll
    for (int mt = 0; mt < 2; ++mt) {
        const int i = mt ? ib : ia;
        const float* wp = w3 + ((size_t)i * CCH + jcol) * 9;
        int ti = 0;
        #pragma unroll
        for (int t = 0; t < 9; ++t) {
            if (t == 4) continue;
            const float val = avalid ? wp[t] : 0.0f;
            const short bv = (short)f2bf(val);
            bf16x8 f;
            #pragma unroll
            for (int e2 = 0; e2 < 8; ++e2) f[e2] = (e2 == epos) ? bv : (short)0;
            ft[mt][ti] = f;
            ++ti;
        }
    }
    float bias_[2][4];
    #pragma unroll
    for (int mt = 0; mt < 2; ++mt) {
        const int chb = (mt ? 32 : 0) + pair * 16 + lq * 4;
        #pragma unroll
        for (int r = 0; r < 4; ++r) bias_[mt][r] = b[chb + r];
    }
    __syncthreads();

    const char* lbase = (const char*)s_x;
    const int c0t = pair * 16 + (lq & 1) * 8 + 32 * (lane >> 5);
    f32x4 acc[4][2];
    #pragma unroll
    for (int g = 0; g < 4; ++g)
        #pragma unroll
        for (int mt = 0; mt < 2; ++mt)
            acc[g][mt] = (f32x4){0.f, 0.f, 0.f, 0.f};

    #pragma unroll
    for (int g = 0; g < 4; ++g) {
        const int row = trow0 + (g >> 1);
        const int gc  = (g & 1) * 16;
        {
            const int p = (row + 1) * HCOLS + gc + l15 + 1;
            #pragma unroll
            for (int kh = 0; kh < 2; ++kh) {
                const int c = kh * 32 + lq * 8;
                const bf16x8 bf = *(const bf16x8*)(lbase + (p << 7) + ((c << 1) ^ ((p & 7) << 4)));
                acc[g][0] = __builtin_amdgcn_mfma_f32_16x16x32_bf16(fc[0][kh], bf, acc[g][0], 0, 0, 0);
                acc[g][1] = __builtin_amdgcn_mfma_f32_16x16x32_bf16(fc[1][kh], bf, acc[g][1], 0, 0, 0);
            }
        }
        int ti = 0;
        #pragma unroll
        for (int t = 0; t < 9; ++t) {
            if (t == 4) continue;
            const int dy = t / 3, dx = t % 3;
            const int p = (row + dy) * HCOLS + gc + l15 + dx;
            const bf16x8 bf = *(const bf16x8*)(lbase + (p << 7) + ((c0t << 1) ^ ((p & 7) << 4)));
            acc[g][0] = __builtin_amdgcn_mfma_f32_16x16x32_bf16(ft[0][ti], bf, acc[g][0], 0, 0, 0);
            acc[g][1] = __builtin_amdgcn_mfma_f32_16x16x32_bf16(ft[1][ti], bf, acc[g][1], 0, 0, 0);
            ++ti;
        }
    }

    #pragma unroll
    for (int g = 0; g < 4; ++g) {
        const int row = trow0 + (g >> 1);
        const int gc  = (g & 1) * 16;
        const int gh  = h0 + row;
        const int gw  = w0 + gc + l15;
        #pragma unroll
        for (int mt = 0; mt < 2; ++mt) {
            const int chb = (mt ? 32 : 0) + pair * 16 + lq * 4;
            #pragma unroll
            for (int r = 0; r < 4; ++r) {
                y[nbase + (size_t)(chb + r) * HW + (size_t)gh * WW + gw] =
                    acc[g][mt][r] + bias_[mt][r];
            }
        }
    }
}

extern "C" void kernel_launch(void* const* d_in, const int* in_sizes, int n_in,
                              void* d_out, int out_size, void* d_ws, size_t ws_size,
                              hipStream_t stream) {
    (void)in_sizes; (void)n_in; (void)out_size;
    const float* x  = (const float*)d_in[0];
    const float* w3 = (const float*)d_in[1];
    const float* w1 = (const float*)d_in[2];
    const float* b  = (const float*)d_in[3];
    float* y = (float*)d_out;

    const size_t need = XQ_BYTES + FRAG_BYTES;
    if (ws_size >= need) {
        unsigned short* xq = (unsigned short*)d_ws;
        u32x4* frag = (u32x4*)((char*)d_ws + XQ_BYTES);
        hipLaunchKernelGGL(build_frags, dim3(1, 1, 1), dim3(128, 1, 1), 0, stream,
                           w3, w1, b, frag);
        hipLaunchKernelGGL(prepass, dim3(PH, NB, 1), dim3(256, 1, 1), 0, stream, x, xq);
        hipLaunchKernelGGL(hetconv_main, dim3(WW / 64, HH / TH, NB), dim3(256, 1, 1),
                           0, stream, xq, frag, y);
    } else {
        hipLaunchKernelGGL(hetconv_mfma, dim3(WW / TW, HH / TH, NB), dim3(256, 1, 1),
                           0, stream, x, w3, w1, b, y);
    }
}

// Round 11
// 146.144 us; speedup vs baseline: 1.4142x; 1.1640x over previous
//
#include <hip/hip_runtime.h>

// HetConv2d, three-phase:
//  0) build_frags: precompute per-(pair,lane) MFMA A-fragments + bias into
//     d_ws (45 KB, L2-resident).
//  1) prepass: x NCHW f32 -> zero-padded NHWC bf16 x' (d_ws), swizzle baked:
//     byte-in-pixel = (c*2) ^ ((wp&7)<<4).
//  2) hetconv_main: round-7 structure (8192 blocks, one 4x32 tile each),
//     global_load_lds staging, taps-outer compute; output transposed through
//     LDS so nt stores are full 128B lines (dwordx4), fixing the 1.26x write
//     amplification of scalar nt stores.
// Fallback: round-2 fused kernel if ws too small.

#define HH 256
#define WW 256
#define CCH 64
#define HW (HH * WW)
#define NB 16
#define PH 258
#define PW 258
#define TH 4
#define TW 32
#define HROWS (TH + 2)              // 6
#define HCOLS (TW + 2)              // 34
#define NPIX (HROWS * HCOLS)        // 204
#define ROWB (HCOLS * CCH * 2)      // 4352 bytes per LDS tile row
#define NCHUNK (NPIX * 8)           // 1632 16B chunks per tile

#define CHS 36                      // f32 stride per channel in store buffer
#define RSTR (CCH * CHS)            // 2304 floats per output row
#define SMEM_BYTES (TH * RSTR * 4)  // 36864 B (> NCHUNK*16 = 26112)

#define XQ_BYTES ((size_t)NB * PH * PW * CCH * 2)   // 136,315,392 (16B-aligned)
#define NSLOT 22                                     // 4 fc + 16 ft + 2 bias
#define FRAG_BYTES (2 * NSLOT * 64 * 16)             // 45056

typedef __attribute__((ext_vector_type(8))) short bf16x8;
typedef __attribute__((ext_vector_type(4))) float f32x4;
typedef __attribute__((ext_vector_type(4))) unsigned int u32x4;

typedef __attribute__((address_space(1))) const unsigned int gu32;
typedef __attribute__((address_space(3))) unsigned int lu32;

__device__ __forceinline__ unsigned short f2bf(float f) {
    unsigned int u = __float_as_uint(f);
    u += 0x7FFFu + ((u >> 16) & 1u);   // RNE
    return (unsigned short)(u >> 16);
}

// ---------------- phase 0: fragment build (1 block, 128 threads) ----------
__global__ __launch_bounds__(128) void build_frags(
    const float* __restrict__ w3, const float* __restrict__ w1,
    const float* __restrict__ b, u32x4* __restrict__ frag)
{
    const int tid = threadIdx.x;
    if (tid >= 128) return;
    const int pair = tid >> 6;
    const int lane = tid & 63;
    const int l15  = lane & 15;
    const int lq   = lane >> 4;

    const int ia = pair * 16 + l15;
    const int ib = ia + 32;

    u32x4* out = frag + (size_t)pair * NSLOT * 64 + lane;

    // fc[mt][kh]: slots 0..3
    #pragma unroll
    for (int mt = 0; mt < 2; ++mt) {
        const int i = mt ? ib : ia;
        #pragma unroll
        for (int kh = 0; kh < 2; ++kh) {
            const int c0 = kh * 32 + lq * 8;
            bf16x8 v;
            #pragma unroll
            for (int e = 0; e < 8; ++e) {
                const int j = c0 + e;
                const float wval = (((j ^ i) & 31) == 0)
                                   ? w3[((size_t)i * CCH + j) * 9 + 4]
                                   : w1[(size_t)i * CCH + j];
                v[e] = (short)f2bf(wval);
            }
            out[(mt * 2 + kh) * 64] = __builtin_bit_cast(u32x4, v);
        }
    }

    // ft[mt][ti]: slots 4..19
    const bool avalid = ((lq & 1) == (l15 >> 3));
    const int  epos   = l15 & 7;
    const int  jcol   = pair * 16 + l15 + 32 * (lane >> 5);
    #pragma unroll
    for (int mt = 0; mt < 2; ++mt) {
        const int i = mt ? ib : ia;
        const float* wp = w3 + ((size_t)i * CCH + jcol) * 9;
        int ti = 0;
        #pragma unroll
        for (int t = 0; t < 9; ++t) {
            if (t == 4) continue;
            const float val = avalid ? wp[t] : 0.0f;
            const short bv = (short)f2bf(val);
            bf16x8 f;
            #pragma unroll
            for (int e2 = 0; e2 < 8; ++e2) f[e2] = (e2 == epos) ? bv : (short)0;
            out[(4 + mt * 8 + ti) * 64] = __builtin_bit_cast(u32x4, f);
            ++ti;
        }
    }

    // bias[mt]: slots 20..21
    #pragma unroll
    for (int mt = 0; mt < 2; ++mt) {
        const int chb = (mt ? 32 : 0) + pair * 16 + lq * 4;
        f32x4 bv = (f32x4){b[chb + 0], b[chb + 1], b[chb + 2], b[chb + 3]};
        out[(20 + mt) * 64] = __builtin_bit_cast(u32x4, bv);
    }
}

// ---------------- phase 1: pre-pass, one padded row per block -------------
__global__ __launch_bounds__(256) void prepass(
    const float* __restrict__ x, unsigned short* __restrict__ xq)
{
    __shared__ __align__(16) unsigned short s[256 * CCH];   // 32 KB
    const int t  = threadIdx.x;
    const int hp = blockIdx.x;            // 0..PH-1
    const int n  = blockIdx.y;
    char* sb = (char*)s;
    unsigned short* rowp = xq + ((size_t)(n * PH + hp)) * PW * CCH;
    const int NCH16 = PW * CCH / 8;       // 2064 16B chunks per padded row

    if (hp == 0 || hp == PH - 1) {
        const u32x4 z = (u32x4){0u, 0u, 0u, 0u};
        for (int i = t; i < NCH16; i += 256)
            *(u32x4*)((char*)rowp + (size_t)i * 16) = z;
        return;
    }

    const int h = hp - 1;
    const float* xp = x + (size_t)n * CCH * HW + (size_t)h * WW + t;  // t = w
    #pragma unroll 4
    for (int c4 = 0; c4 < CCH; c4 += 4) {
        float v0 = __builtin_nontemporal_load(xp + (size_t)(c4 + 0) * HW);
        float v1 = __builtin_nontemporal_load(xp + (size_t)(c4 + 1) * HW);
        float v2 = __builtin_nontemporal_load(xp + (size_t)(c4 + 2) * HW);
        float v3 = __builtin_nontemporal_load(xp + (size_t)(c4 + 3) * HW);
        uint2 pk;
        pk.x = (unsigned)f2bf(v0) | ((unsigned)f2bf(v1) << 16);
        pk.y = (unsigned)f2bf(v2) | ((unsigned)f2bf(v3) << 16);
        *(uint2*)(sb + (t << 7) + ((c4 << 1) ^ ((t & 7) << 4))) = pk;
    }
    __syncthreads();

    for (int i = t; i < NCH16; i += 256) {
        const int wp = i >> 3;
        const int s8 = i & 7;
        u32x4 v;
        if (wp == 0 || wp == PW - 1) {
            v = (u32x4){0u, 0u, 0u, 0u};
        } else {
            const int r = wp - 1;
            const int cslot = s8 ^ (wp & 7);
            v = *(const u32x4*)(sb + (r << 7) + ((cslot ^ (r & 7)) << 4));
        }
        *(u32x4*)((char*)rowp + (size_t)i * 16) = v;
    }
}

// ---------------- phase 2: main conv (taps-outer + store transpose) -------
__global__ __launch_bounds__(256, 3) void hetconv_main(
    const unsigned short* __restrict__ xq, const u32x4* __restrict__ frag,
    float* __restrict__ y)
{
    __shared__ __align__(16) char smem[SMEM_BYTES];   // staging (26 KB) then store buf (36 KB)

    const int tid  = threadIdx.x;
    const int lane = tid & 63;
    const int wv   = tid >> 6;
    const int l15  = lane & 15;
    const int lq   = lane >> 4;
    const int pair  = wv & 1;
    const int trow0 = (wv >> 1) * 2;

    const int n  = blockIdx.z;
    const int h0 = blockIdx.y * TH;      // padded top row of tile (== image top row of output)
    const int w0 = blockIdx.x * TW;      // padded left col (w0 % 8 == 0)
    const size_t nbase = (size_t)n * CCH * HW;

    // ---- stage tile: 1632 coalesced 16B chunks, linear LDS ----
    {
        const unsigned short* gsrc =
            xq + ((size_t)(n * PH + h0) * PW + w0) * CCH;
        #pragma unroll
        for (int it = 0; it < 7; ++it) {
            const int ck = it * 256 + tid;
            if (it < 6 || tid < (NCHUNK - 6 * 256)) {
                const int r = ck / (HCOLS * 8);            // 272 chunks/row
                const int o = ck - r * (HCOLS * 8);
                const unsigned short* gp = gsrc + (size_t)r * PW * CCH + o * 8;
                __builtin_amdgcn_global_load_lds(
                    (gu32*)(const void*)gp,
                    (lu32*)(void*)(smem + ck * 16), 16, 0, 0);
            }
        }
    }

    __syncthreads();

    // ---- compute from LDS, taps outer / pixel-group inner ----
    const char* lbase = (const char*)smem;
    const u32x4* fb = frag + (size_t)pair * NSLOT * 64 + lane;
    const int c0t = pair * 16 + (lq & 1) * 8 + 32 * (lane >> 5);

    f32x4 acc[4][2];
    #pragma unroll
    for (int g = 0; g < 4; ++g)
        #pragma unroll
        for (int mt = 0; mt < 2; ++mt)
            acc[g][mt] = (f32x4){0.f, 0.f, 0.f, 0.f};

    // center tap (dy=1, dx=1): dense K=64, fc fragments slots 0..3
    #pragma unroll
    for (int kh = 0; kh < 2; ++kh) {
        const bf16x8 f0 = __builtin_bit_cast(bf16x8, fb[(0 * 2 + kh) * 64]);
        const bf16x8 f1 = __builtin_bit_cast(bf16x8, fb[(1 * 2 + kh) * 64]);
        const int c = kh * 32 + lq * 8;
        #pragma unroll
        for (int g = 0; g < 4; ++g) {
            const int row = trow0 + (g >> 1);
            const int p   = (g & 1) * 16 + l15 + 1;
            const bf16x8 bf = *(const bf16x8*)(lbase + (row + 1) * ROWB + (p << 7)
                                               + ((c << 1) ^ ((p & 7) << 4)));
            acc[g][0] = __builtin_amdgcn_mfma_f32_16x16x32_bf16(f0, bf, acc[g][0], 0, 0, 0);
            acc[g][1] = __builtin_amdgcn_mfma_f32_16x16x32_bf16(f1, bf, acc[g][1], 0, 0, 0);
        }
    }

    // 8 off-center taps, packed K=32, ft fragments slots 4..19
    {
        int ti = 0;
        #pragma unroll
        for (int t = 0; t < 9; ++t) {
            if (t == 4) continue;
            const int dy = t / 3, dx = t % 3;
            const bf16x8 f0 = __builtin_bit_cast(bf16x8, fb[(4 + ti) * 64]);
            const bf16x8 f1 = __builtin_bit_cast(bf16x8, fb[(4 + 8 + ti) * 64]);
            #pragma unroll
            for (int g = 0; g < 4; ++g) {
                const int row = trow0 + (g >> 1);
                const int p   = (g & 1) * 16 + l15 + dx;
                const bf16x8 bf = *(const bf16x8*)(lbase + (row + dy) * ROWB + (p << 7)
                                                   + ((c0t << 1) ^ ((p & 7) << 4)));
                acc[g][0] = __builtin_amdgcn_mfma_f32_16x16x32_bf16(f0, bf, acc[g][0], 0, 0, 0);
                acc[g][1] = __builtin_amdgcn_mfma_f32_16x16x32_bf16(f1, bf, acc[g][1], 0, 0, 0);
            }
            ++ti;
        }
    }

    // bias (slots 20..21)
    f32x4 bias_[2];
    #pragma unroll
    for (int mt = 0; mt < 2; ++mt)
        bias_[mt] = __builtin_bit_cast(f32x4, fb[(20 + mt) * 64]);

    // ---- store transpose: acc -> LDS [row][ch*CHS + px] ----
    __syncthreads();                       // all LDS reads of x-tile complete
    float* sy = (float*)smem;
    #pragma unroll
    for (int g = 0; g < 4; ++g) {
        const int row = trow0 + (g >> 1);
        const int px  = (g & 1) * 16 + l15;
        #pragma unroll
        for (int mt = 0; mt < 2; ++mt) {
            const int chb = (mt ? 32 : 0) + pair * 16 + lq * 4;
            #pragma unroll
            for (int r = 0; r < 4; ++r) {
                sy[row * RSTR + (chb + r) * CHS + px] = acc[g][mt][r] + bias_[mt][r];
            }
        }
    }
    __syncthreads();

    // ---- wide nt stores: 8 x dwordx4 per thread, full 128B lines ----
    #pragma unroll
    for (int i2 = 0; i2 < 8; ++i2) {
        const int idx = i2 * 256 + tid;         // 0..2047
        const int row = idx >> 9;               // 0..3
        const int rem = idx & 511;
        const int ch  = rem >> 3;               // 0..63
        const int q   = rem & 7;                // 0..7 (pixel quad)
        const f32x4 v = *(const f32x4*)(sy + row * RSTR + ch * CHS + q * 4);
        float* dst = y + nbase + (size_t)ch * HW + (size_t)(h0 + row) * WW + w0 + q * 4;
        __builtin_nontemporal_store(v, (f32x4*)dst);
    }
}

// ---------------- fallback: round-2 fused kernel (proven) ----------------
__global__ __launch_bounds__(256, 2) void hetconv_mfma(
    const float* __restrict__ x, const float* __restrict__ w3,
    const float* __restrict__ w1, const float* __restrict__ b,
    float* __restrict__ y)
{
    __shared__ __align__(16) unsigned short s_x[NPIX * CCH];

    const int tid  = threadIdx.x;
    const int lane = tid & 63;
    const int wv   = tid >> 6;
    const int l15  = lane & 15;
    const int lq   = lane >> 4;
    const int pair  = wv & 1;
    const int trow0 = (wv >> 1) * 2;

    const int n  = blockIdx.z;
    const int h0 = blockIdx.y * TH;
    const int w0 = blockIdx.x * TW;
    const size_t nbase = (size_t)n * CCH * HW;

    if (tid < NPIX) {
        const int r = tid / HCOLS;
        const int c = tid - r * HCOLS;
        const int gh = h0 + r - 1;
        const int gw = w0 + c - 1;
        const bool inb = ((unsigned)gh < HH) && ((unsigned)gw < WW);
        const float* xp = x + nbase + (size_t)(inb ? gh : 0) * WW + (inb ? gw : 0);
        char* lbase = (char*)s_x;
        #pragma unroll 4
        for (int c4 = 0; c4 < CCH; c4 += 4) {
            float v0 = inb ? xp[(size_t)(c4 + 0) * HW] : 0.0f;
            float v1 = inb ? xp[(size_t)(c4 + 1) * HW] : 0.0f;
            float v2 = inb ? xp[(size_t)(c4 + 2) * HW] : 0.0f;
            float v3 = inb ? xp[(size_t)(c4 + 3) * HW] : 0.0f;
            uint2 pk;
            pk.x = (unsigned)f2bf(v0) | ((unsigned)f2bf(v1) << 16);
            pk.y = (unsigned)f2bf(v2) | ((unsigned)f2bf(v3) << 16);
            *(uint2*)(lbase + (tid << 7) + ((c4 << 1) ^ ((tid & 7) << 4))) = pk;
        }
    }

    const int ia = pair * 16 + l15;
    const int ib = ia + 32;
    bf16x8 fc[2][2];
    #pragma unroll
    for (int mt = 0; mt < 2; ++mt) {
        const int i = mt ? ib : ia;
        #pragma unroll
        for (int kh = 0; kh < 2; ++kh) {
            const int c0 = kh * 32 + lq * 8;
            bf16x8 v;
            #pragma unroll
            for (int e = 0; e < 8; ++e) {
                const int j = c0 + e;
                const float wval = (((j ^ i) & 31) == 0)
                                   ? w3[((size_t)i * CCH + j) * 9 + 4]
                                   : w1[(size_t)i * CCH + j];
                v[e] = (short)f2bf(wval);
            }
            fc[mt][kh] = v;
        }
    }
    const bool avalid = ((lq & 1) == (l15 >> 3));
    const int  epos   = l15 & 7;
    const int  jcol   = pair * 16 + l15 + 32 * (lane >> 5);
    bf16x8 ft[2][8];
    #pragma unroll
    for (int mt = 0; mt < 2; ++mt) {
        const int i = mt ? ib : ia;
        const float* wp = w3 + ((size_t)i * CCH + jcol) * 9;
        int ti = 0;
        #pragma unroll
        for (int t = 0; t < 9; ++t) {
            if (t == 4) continue;
            const float val = avalid ? wp[t] : 0.0f;
            const short bv = (short)f2bf(val);
            bf16x8 f;
            #pragma unroll
            for (int e2 = 0; e2 < 8; ++e2) f[e2] = (e2 == epos) ? bv : (short)0;
            ft[mt][ti] = f;
            ++ti;
        }
    }
    float bias_[2][4];
    #pragma unroll
    for (int mt = 0; mt < 2; ++mt) {
        const int chb = (mt ? 32 : 0) + pair * 16 + lq * 4;
        #pragma unroll
        for (int r = 0; r < 4; ++r) bias_[mt][r] = b[chb + r];
    }
    __syncthreads();

    const char* lbase = (const char*)s_x;
    const int c0t = pair * 16 + (lq & 1) * 8 + 32 * (lane >> 5);
    f32x4 acc[4][2];
    #pragma unroll
    for (int g = 0; g < 4; ++g)
        #pragma unroll
        for (int mt = 0; mt < 2; ++mt)
            acc[g][mt] = (f32x4){0.f, 0.f, 0.f, 0.f};

    #pragma unroll
    for (int g = 0; g < 4; ++g) {
        const int row = trow0 + (g >> 1);
        const int gc  = (g & 1) * 16;
        {
            const int p = (row + 1) * HCOLS + gc + l15 + 1;
            #pragma unroll
            for (int kh = 0; kh < 2; ++kh) {
                const int c = kh * 32 + lq * 8;
                const bf16x8 bf = *(const bf16x8*)(lbase + (p << 7) + ((c << 1) ^ ((p & 7) << 4)));
                acc[g][0] = __builtin_amdgcn_mfma_f32_16x16x32_bf16(fc[0][kh], bf, acc[g][0], 0, 0, 0);
                acc[g][1] = __builtin_amdgcn_mfma_f32_16x16x32_bf16(fc[1][kh], bf, acc[g][1], 0, 0, 0);
            }
        }
        int ti = 0;
        #pragma unroll
        for (int t = 0; t < 9; ++t) {
            if (t == 4) continue;
            const int dy = t / 3, dx = t % 3;
            const int p = (row + dy) * HCOLS + gc + l15 + dx;
            const bf16x8 bf = *(const bf16x8*)(lbase + (p << 7) + ((c0t << 1) ^ ((p & 7) << 4)));
            acc[g][0] = __builtin_amdgcn_mfma_f32_16x16x32_bf16(ft[0][ti], bf, acc[g][0], 0, 0, 0);
            acc[g][1] = __builtin_amdgcn_mfma_f32_16x16x32_bf16(ft[1][ti], bf, acc[g][1], 0, 0, 0);
            ++ti;
        }
    }

    #pragma unroll
    for (int g = 0; g < 4; ++g) {
        const int row = trow0 + (g >> 1);
        const int gc  = (g & 1) * 16;
        const int gh  = h0 + row;
        const int gw  = w0 + gc + l15;
        #pragma unroll
        for (int mt = 0; mt < 2; ++mt) {
            const int chb = (mt ? 32 : 0) + pair * 16 + lq * 4;
            #pragma unroll
            for (int r = 0; r < 4; ++r) {
                y[nbase + (size_t)(chb + r) * HW + (size_t)gh * WW + gw] =
                    acc[g][mt][r] + bias_[mt][r];
            }
        }
    }
}

extern "C" void kernel_launch(void* const* d_in, const int* in_sizes, int n_in,
                              void* d_out, int out_size, void* d_ws, size_t ws_size,
                              hipStream_t stream) {
    (void)in_sizes; (void)n_in; (void)out_size;
    const float* x  = (const float*)d_in[0];
    const float* w3 = (const float*)d_in[1];
    const float* w1 = (const float*)d_in[2];
    const float* b  = (const float*)d_in[3];
    float* y = (float*)d_out;

    const size_t need = XQ_BYTES + FRAG_BYTES;
    if (ws_size >= need) {
        unsigned short* xq = (unsigned short*)d_ws;
        u32x4* frag = (u32x4*)((char*)d_ws + XQ_BYTES);
        hipLaunchKernelGGL(build_frags, dim3(1, 1, 1), dim3(128, 1, 1), 0, stream,
                           w3, w1, b, frag);
        hipLaunchKernelGGL(prepass, dim3(PH, NB, 1), dim3(256, 1, 1), 0, stream, x, xq);
        hipLaunchKernelGGL(hetconv_main, dim3(WW / TW, HH / TH, NB), dim3(256, 1, 1),
                           0, stream, xq, frag, y);
    } else {
        hipLaunchKernelGGL(hetconv_mfma, dim3(WW / TW, HH / TH, NB), dim3(256, 1, 1),
                           0, stream, x, w3, w1, b, y);
    }
}

// Round 12
// 138.844 us; speedup vs baseline: 1.4886x; 1.0526x over previous
//
#include <hip/hip_runtime.h>

// HetConv2d, two-phase:
//  1) prepass: x NCHW f32 -> zero-padded NHWC bf16 x' (d_ws), swizzle baked:
//     byte-in-pixel = (c*2) ^ ((wp&7)<<4). The (hp==0,n==0) border block also
//     builds the MFMA A-fragments + bias into d_ws (45 KB) — folds the old
//     build_frags kernel into this launch.
//  2) hetconv_main: 8192 blocks, one 4x32 tile each; global_load_lds staging,
//     taps-outer compute, store-transpose through LDS -> full-line nt stores.
//     launch_bounds(256,4): 4 blocks/CU (LDS 4x36.9=148<=160, VGPR cap 128).
// Fallback: round-2 fused kernel if ws too small.

#define HH 256
#define WW 256
#define CCH 64
#define HW (HH * WW)
#define NB 16
#define PH 258
#define PW 258
#define TH 4
#define TW 32
#define HROWS (TH + 2)              // 6
#define HCOLS (TW + 2)              // 34
#define NPIX (HROWS * HCOLS)        // 204
#define ROWB (HCOLS * CCH * 2)      // 4352 bytes per LDS tile row
#define NCHUNK (NPIX * 8)           // 1632 16B chunks per tile

#define CHS 36                      // f32 stride per channel in store buffer
#define RSTR (CCH * CHS)            // 2304 floats per output row
#define SMEM_BYTES (TH * RSTR * 4)  // 36864 B (> NCHUNK*16 = 26112)

#define XQ_BYTES ((size_t)NB * PH * PW * CCH * 2)   // 136,315,392 (16B-aligned)
#define NSLOT 22                                     // 4 fc + 16 ft + 2 bias
#define FRAG_BYTES (2 * NSLOT * 64 * 16)             // 45056

typedef __attribute__((ext_vector_type(8))) short bf16x8;
typedef __attribute__((ext_vector_type(4))) float f32x4;
typedef __attribute__((ext_vector_type(4))) unsigned int u32x4;

typedef __attribute__((address_space(1))) const unsigned int gu32;
typedef __attribute__((address_space(3))) unsigned int lu32;

__device__ __forceinline__ unsigned short f2bf(float f) {
    unsigned int u = __float_as_uint(f);
    u += 0x7FFFu + ((u >> 16) & 1u);   // RNE
    return (unsigned short)(u >> 16);
}

// ---------------- fragment build (device helper, 128 threads) -------------
__device__ __forceinline__ void build_frags_dev(
    const float* __restrict__ w3, const float* __restrict__ w1,
    const float* __restrict__ b, u32x4* __restrict__ frag, int tid)
{
    const int pair = tid >> 6;
    const int lane = tid & 63;
    const int l15  = lane & 15;
    const int lq   = lane >> 4;

    const int ia = pair * 16 + l15;
    const int ib = ia + 32;

    u32x4* out = frag + (size_t)pair * NSLOT * 64 + lane;

    // fc[mt][kh]: slots 0..3
    #pragma unroll
    for (int mt = 0; mt < 2; ++mt) {
        const int i = mt ? ib : ia;
        #pragma unroll
        for (int kh = 0; kh < 2; ++kh) {
            const int c0 = kh * 32 + lq * 8;
            bf16x8 v;
            #pragma unroll
            for (int e = 0; e < 8; ++e) {
                const int j = c0 + e;
                const float wval = (((j ^ i) & 31) == 0)
                                   ? w3[((size_t)i * CCH + j) * 9 + 4]
                                   : w1[(size_t)i * CCH + j];
                v[e] = (short)f2bf(wval);
            }
            out[(mt * 2 + kh) * 64] = __builtin_bit_cast(u32x4, v);
        }
    }

    // ft[mt][ti]: slots 4..19
    const bool avalid = ((lq & 1) == (l15 >> 3));
    const int  epos   = l15 & 7;
    const int  jcol   = pair * 16 + l15 + 32 * (lane >> 5);
    #pragma unroll
    for (int mt = 0; mt < 2; ++mt) {
        const int i = mt ? ib : ia;
        const float* wp = w3 + ((size_t)i * CCH + jcol) * 9;
        int ti = 0;
        #pragma unroll
        for (int t = 0; t < 9; ++t) {
            if (t == 4) continue;
            const float val = avalid ? wp[t] : 0.0f;
            const short bv = (short)f2bf(val);
            bf16x8 f;
            #pragma unroll
            for (int e2 = 0; e2 < 8; ++e2) f[e2] = (e2 == epos) ? bv : (short)0;
            out[(4 + mt * 8 + ti) * 64] = __builtin_bit_cast(u32x4, f);
            ++ti;
        }
    }

    // bias[mt]: slots 20..21
    #pragma unroll
    for (int mt = 0; mt < 2; ++mt) {
        const int chb = (mt ? 32 : 0) + pair * 16 + lq * 4;
        f32x4 bv = (f32x4){b[chb + 0], b[chb + 1], b[chb + 2], b[chb + 3]};
        out[(20 + mt) * 64] = __builtin_bit_cast(u32x4, bv);
    }
}

// ---------------- phase 1: pre-pass, one padded row per block -------------
__global__ __launch_bounds__(256) void prepass(
    const float* __restrict__ x, unsigned short* __restrict__ xq,
    const float* __restrict__ w3, const float* __restrict__ w1,
    const float* __restrict__ b, u32x4* __restrict__ frag)
{
    __shared__ __align__(16) unsigned short s[256 * CCH];   // 32 KB
    const int t  = threadIdx.x;
    const int hp = blockIdx.x;            // 0..PH-1
    const int n  = blockIdx.y;
    char* sb = (char*)s;
    unsigned short* rowp = xq + ((size_t)(n * PH + hp)) * PW * CCH;
    const int NCH16 = PW * CCH / 8;       // 2064 16B chunks per padded row

    if (hp == 0 || hp == PH - 1) {
        const u32x4 z = (u32x4){0u, 0u, 0u, 0u};
        for (int i = t; i < NCH16; i += 256)
            *(u32x4*)((char*)rowp + (size_t)i * 16) = z;
        if (hp == 0 && n == 0 && t < 128)
            build_frags_dev(w3, w1, b, frag, t);
        return;
    }

    const int h = hp - 1;
    const float* xp = x + (size_t)n * CCH * HW + (size_t)h * WW + t;  // t = w
    #pragma unroll 4
    for (int c4 = 0; c4 < CCH; c4 += 4) {
        float v0 = __builtin_nontemporal_load(xp + (size_t)(c4 + 0) * HW);
        float v1 = __builtin_nontemporal_load(xp + (size_t)(c4 + 1) * HW);
        float v2 = __builtin_nontemporal_load(xp + (size_t)(c4 + 2) * HW);
        float v3 = __builtin_nontemporal_load(xp + (size_t)(c4 + 3) * HW);
        uint2 pk;
        pk.x = (unsigned)f2bf(v0) | ((unsigned)f2bf(v1) << 16);
        pk.y = (unsigned)f2bf(v2) | ((unsigned)f2bf(v3) << 16);
        *(uint2*)(sb + (t << 7) + ((c4 << 1) ^ ((t & 7) << 4))) = pk;
    }
    __syncthreads();

    for (int i = t; i < NCH16; i += 256) {
        const int wp = i >> 3;
        const int s8 = i & 7;
        u32x4 v;
        if (wp == 0 || wp == PW - 1) {
            v = (u32x4){0u, 0u, 0u, 0u};
        } else {
            const int r = wp - 1;
            const int cslot = s8 ^ (wp & 7);
            v = *(const u32x4*)(sb + (r << 7) + ((cslot ^ (r & 7)) << 4));
        }
        *(u32x4*)((char*)rowp + (size_t)i * 16) = v;
    }
}

// ---------------- phase 2: main conv (taps-outer + store transpose) -------
__global__ __launch_bounds__(256, 4) void hetconv_main(
    const unsigned short* __restrict__ xq, const u32x4* __restrict__ frag,
    float* __restrict__ y)
{
    __shared__ __align__(16) char smem[SMEM_BYTES];   // staging (26 KB) then store buf (36 KB)

    const int tid  = threadIdx.x;
    const int lane = tid & 63;
    const int wv   = tid >> 6;
    const int l15  = lane & 15;
    const int lq   = lane >> 4;
    const int pair  = wv & 1;
    const int trow0 = (wv >> 1) * 2;

    const int n  = blockIdx.z;
    const int h0 = blockIdx.y * TH;      // padded top row of tile (== image top row of output)
    const int w0 = blockIdx.x * TW;      // padded left col (w0 % 8 == 0)
    const size_t nbase = (size_t)n * CCH * HW;

    // ---- stage tile: 1632 coalesced 16B chunks, linear LDS ----
    {
        const unsigned short* gsrc =
            xq + ((size_t)(n * PH + h0) * PW + w0) * CCH;
        #pragma unroll
        for (int it = 0; it < 7; ++it) {
            const int ck = it * 256 + tid;
            if (it < 6 || tid < (NCHUNK - 6 * 256)) {
                const int r = ck / (HCOLS * 8);            // 272 chunks/row
                const int o = ck - r * (HCOLS * 8);
                const unsigned short* gp = gsrc + (size_t)r * PW * CCH + o * 8;
                __builtin_amdgcn_global_load_lds(
                    (gu32*)(const void*)gp,
                    (lu32*)(void*)(smem + ck * 16), 16, 0, 0);
            }
        }
    }

    __syncthreads();

    // ---- compute from LDS, taps outer / pixel-group inner ----
    const char* lbase = (const char*)smem;
    const u32x4* fb = frag + (size_t)pair * NSLOT * 64 + lane;
    const int c0t = pair * 16 + (lq & 1) * 8 + 32 * (lane >> 5);

    f32x4 acc[4][2];
    #pragma unroll
    for (int g = 0; g < 4; ++g)
        #pragma unroll
        for (int mt = 0; mt < 2; ++mt)
            acc[g][mt] = (f32x4){0.f, 0.f, 0.f, 0.f};

    // center tap (dy=1, dx=1): dense K=64, fc fragments slots 0..3
    #pragma unroll
    for (int kh = 0; kh < 2; ++kh) {
        const bf16x8 f0 = __builtin_bit_cast(bf16x8, fb[(0 * 2 + kh) * 64]);
        const bf16x8 f1 = __builtin_bit_cast(bf16x8, fb[(1 * 2 + kh) * 64]);
        const int c = kh * 32 + lq * 8;
        #pragma unroll
        for (int g = 0; g < 4; ++g) {
            const int row = trow0 + (g >> 1);
            const int p   = (g & 1) * 16 + l15 + 1;
            const bf16x8 bf = *(const bf16x8*)(lbase + (row + 1) * ROWB + (p << 7)
                                               + ((c << 1) ^ ((p & 7) << 4)));
            acc[g][0] = __builtin_amdgcn_mfma_f32_16x16x32_bf16(f0, bf, acc[g][0], 0, 0, 0);
            acc[g][1] = __builtin_amdgcn_mfma_f32_16x16x32_bf16(f1, bf, acc[g][1], 0, 0, 0);
        }
    }

    // 8 off-center taps, packed K=32, ft fragments slots 4..19
    {
        int ti = 0;
        #pragma unroll
        for (int t = 0; t < 9; ++t) {
            if (t == 4) continue;
            const int dy = t / 3, dx = t % 3;
            const bf16x8 f0 = __builtin_bit_cast(bf16x8, fb[(4 + ti) * 64]);
            const bf16x8 f1 = __builtin_bit_cast(bf16x8, fb[(4 + 8 + ti) * 64]);
            #pragma unroll
            for (int g = 0; g < 4; ++g) {
                const int row = trow0 + (g >> 1);
                const int p   = (g & 1) * 16 + l15 + dx;
                const bf16x8 bf = *(const bf16x8*)(lbase + (row + dy) * ROWB + (p << 7)
                                                   + ((c0t << 1) ^ ((p & 7) << 4)));
                acc[g][0] = __builtin_amdgcn_mfma_f32_16x16x32_bf16(f0, bf, acc[g][0], 0, 0, 0);
                acc[g][1] = __builtin_amdgcn_mfma_f32_16x16x32_bf16(f1, bf, acc[g][1], 0, 0, 0);
            }
            ++ti;
        }
    }

    // bias (slots 20..21)
    f32x4 bias_[2];
    #pragma unroll
    for (int mt = 0; mt < 2; ++mt)
        bias_[mt] = __builtin_bit_cast(f32x4, fb[(20 + mt) * 64]);

    // ---- store transpose: acc -> LDS [row][ch*CHS + px] ----
    __syncthreads();                       // all LDS reads of x-tile complete
    float* sy = (float*)smem;
    #pragma unroll
    for (int g = 0; g < 4; ++g) {
        const int row = trow0 + (g >> 1);
        const int px  = (g & 1) * 16 + l15;
        #pragma unroll
        for (int mt = 0; mt < 2; ++mt) {
            const int chb = (mt ? 32 : 0) + pair * 16 + lq * 4;
            #pragma unroll
            for (int r = 0; r < 4; ++r) {
                sy[row * RSTR + (chb + r) * CHS + px] = acc[g][mt][r] + bias_[mt][r];
            }
        }
    }
    __syncthreads();

    // ---- wide nt stores: 8 x dwordx4 per thread, full 128B lines ----
    #pragma unroll
    for (int i2 = 0; i2 < 8; ++i2) {
        const int idx = i2 * 256 + tid;         // 0..2047
        const int row = idx >> 9;               // 0..3
        const int rem = idx & 511;
        const int ch  = rem >> 3;               // 0..63
        const int q   = rem & 7;                // 0..7 (pixel quad)
        const f32x4 v = *(const f32x4*)(sy + row * RSTR + ch * CHS + q * 4);
        float* dst = y + nbase + (size_t)ch * HW + (size_t)(h0 + row) * WW + w0 + q * 4;
        __builtin_nontemporal_store(v, (f32x4*)dst);
    }
}

// ---------------- fallback: round-2 fused kernel (proven) ----------------
__global__ __launch_bounds__(256, 2) void hetconv_mfma(
    const float* __restrict__ x, const float* __restrict__ w3,
    const float* __restrict__ w1, const float* __restrict__ b,
    float* __restrict__ y)
{
    __shared__ __align__(16) unsigned short s_x[NPIX * CCH];

    const int tid  = threadIdx.x;
    const int lane = tid & 63;
    const int wv   = tid >> 6;
    const int l15  = lane & 15;
    const int lq   = lane >> 4;
    const int pair  = wv & 1;
    const int trow0 = (wv >> 1) * 2;

    const int n  = blockIdx.z;
    const int h0 = blockIdx.y * TH;
    const int w0 = blockIdx.x * TW;
    const size_t nbase = (size_t)n * CCH * HW;

    if (tid < NPIX) {
        const int r = tid / HCOLS;
        const int c = tid - r * HCOLS;
        const int gh = h0 + r - 1;
        const int gw = w0 + c - 1;
        const bool inb = ((unsigned)gh < HH) && ((unsigned)gw < WW);
        const float* xp = x + nbase + (size_t)(inb ? gh : 0) * WW + (inb ? gw : 0);
        char* lbase = (char*)s_x;
        #pragma unroll 4
        for (int c4 = 0; c4 < CCH; c4 += 4) {
            float v0 = inb ? xp[(size_t)(c4 + 0) * HW] : 0.0f;
            float v1 = inb ? xp[(size_t)(c4 + 1) * HW] : 0.0f;
            float v2 = inb ? xp[(size_t)(c4 + 2) * HW] : 0.0f;
            float v3 = inb ? xp[(size_t)(c4 + 3) * HW] : 0.0f;
            uint2 pk;
            pk.x = (unsigned)f2bf(v0) | ((unsigned)f2bf(v1) << 16);
            pk.y = (unsigned)f2bf(v2) | ((unsigned)f2bf(v3) << 16);
            *(uint2*)(lbase + (tid << 7) + ((c4 << 1) ^ ((tid & 7) << 4))) = pk;
        }
    }

    const int ia = pair * 16 + l15;
    const int ib = ia + 32;
    bf16x8 fc[2][2];
    #pragma unroll
    for (int mt = 0; mt < 2; ++mt) {
        const int i = mt ? ib : ia;
        #pragma unroll
        for (int kh = 0; kh < 2; ++kh) {
            const int c0 = kh * 32 + lq * 8;
            bf16x8 v;
            #pragma unroll
            for (int e = 0; e < 8; ++e) {
                const int j = c0 + e;
                const float wval = (((j ^ i) & 31) == 0)
                                   ? w3[((size_t)i * CCH + j) * 9 + 4]
                                   : w1[(size_t)i * CCH + j];
                v[e] = (short)f2bf(wval);
            }
            fc[mt][kh] = v;
        }
    }
    const bool avalid = ((lq & 1) == (l15 >> 3));
    const int  epos   = l15 & 7;
    const int  jcol   = pair * 16 + l15 + 32 * (lane >> 5);
    bf16x8 ft[2][8];
    #pragma unroll
    for (int mt = 0; mt < 2; ++mt) {
        const int i = mt ? ib : ia;
        const float* wp = w3 + ((size_t)i * CCH + jcol) * 9;
        int ti = 0;
        #pragma unroll
        for (int t = 0; t < 9; ++t) {
            if (t == 4) continue;
            const float val = avalid ? wp[t] : 0.0f;
            const short bv = (short)f2bf(val);
            bf16x8 f;
            #pragma unroll
            for (int e2 = 0; e2 < 8; ++e2) f[e2] = (e2 == epos) ? bv : (short)0;
            ft[mt][ti] = f;
            ++ti;
        }
    }
    float bias_[2][4];
    #pragma unroll
    for (int mt = 0; mt < 2; ++mt) {
        const int chb = (mt ? 32 : 0) + pair * 16 + lq * 4;
        #pragma unroll
        for (int r = 0; r < 4; ++r) bias_[mt][r] = b[chb + r];
    }
    __syncthreads();

    const char* lbase = (const char*)s_x;
    const int c0t = pair * 16 + (lq & 1) * 8 + 32 * (lane >> 5);
    f32x4 acc[4][2];
    #pragma unroll
    for (int g = 0; g < 4; ++g)
        #pragma unroll
        for (int mt = 0; mt < 2; ++mt)
            acc[g][mt] = (f32x4){0.f, 0.f, 0.f, 0.f};

    #pragma unroll
    for (int g = 0; g < 4; ++g) {
        const int row = trow0 + (g >> 1);
        const int gc  = (g & 1) * 16;
        {
            const int p = (row + 1) * HCOLS + gc + l15 + 1;
            #pragma unroll
            for (int kh = 0; kh < 2; ++kh) {
                const int c = kh * 32 + lq * 8;
                const bf16x8 bf = *(const bf16x8*)(lbase + (p << 7) + ((c << 1) ^ ((p & 7) << 4)));
                acc[g][0] = __builtin_amdgcn_mfma_f32_16x16x32_bf16(fc[0][kh], bf, acc[g][0], 0, 0, 0);
                acc[g][1] = __builtin_amdgcn_mfma_f32_16x16x32_bf16(fc[1][kh], bf, acc[g][1], 0, 0, 0);
            }
        }
        int ti = 0;
        #pragma unroll
        for (int t = 0; t < 9; ++t) {
            if (t == 4) continue;
            const int dy = t / 3, dx = t % 3;
            const int p = (row + dy) * HCOLS + gc + l15 + dx;
            const bf16x8 bf = *(const bf16x8*)(lbase + (p << 7) + ((c0t << 1) ^ ((p & 7) << 4)));
            acc[g][0] = __builtin_amdgcn_mfma_f32_16x16x32_bf16(ft[0][ti], bf, acc[g][0], 0, 0, 0);
            acc[g][1] = __builtin_amdgcn_mfma_f32_16x16x32_bf16(ft[1][ti], bf, acc[g][1], 0, 0, 0);
            ++ti;
        }
    }

    #pragma unroll
    for (int g = 0; g < 4; ++g) {
        const int row = trow0 + (g >> 1);
        const int gc  = (g & 1) * 16;
        const int gh  = h0 + row;
        const int gw  = w0 + gc + l15;
        #pragma unroll
        for (int mt = 0; mt < 2; ++mt) {
            const int chb = (mt ? 32 : 0) + pair * 16 + lq * 4;
            #pragma unroll
            for (int r = 0; r < 4; ++r) {
                y[nbase + (size_t)(chb + r) * HW + (size_t)gh * WW + gw] =
                    acc[g][mt][r] + bias_[mt][r];
            }
        }
    }
}

extern "C" void kernel_launch(void* const* d_in, const int* in_sizes, int n_in,
                              void* d_out, int out_size, void* d_ws, size_t ws_size,
                              hipStream_t stream) {
    (void)in_sizes; (void)n_in; (void)out_size;
    const float* x  = (const float*)d_in[0];
    const float* w3 = (const float*)d_in[1];
    const float* w1 = (const float*)d_in[2];
    const float* b  = (const float*)d_in[3];
    float* y = (float*)d_out;

    const size_t need = XQ_BYTES + FRAG_BYTES;
    if (ws_size >= need) {
        unsigned short* xq = (unsigned short*)d_ws;
        u32x4* frag = (u32x4*)((char*)d_ws + XQ_BYTES);
        hipLaunchKernelGGL(prepass, dim3(PH, NB, 1), dim3(256, 1, 1), 0, stream,
                           x, xq, w3, w1, b, frag);
        hipLaunchKernelGGL(hetconv_main, dim3(WW / TW, HH / TH, NB), dim3(256, 1, 1),
                           0, stream, xq, frag, y);
    } else {
        hipLaunchKernelGGL(hetconv_mfma, dim3(WW / TW, HH / TH, NB), dim3(256, 1, 1),
                           0, stream, x, w3, w1, b, y);
    }
}